// Round 3
// baseline (2231.017 us; speedup 1.0000x reference)
//
#include <hip/hip_runtime.h>
#include <stdint.h>

typedef unsigned short u16;
typedef __attribute__((ext_vector_type(8))) short sx8;   // 8 bf16 (4 VGPRs) — MFMA A/B frag
typedef __attribute__((ext_vector_type(4))) short sx4;
typedef __attribute__((ext_vector_type(4))) float fx4;   // MFMA C/D frag

__device__ __forceinline__ float bf2f(u16 u) {
    union { unsigned i; float f; } v; v.i = ((unsigned)u) << 16; return v.f;
}
__device__ __forceinline__ u16 f2bf(float f) {
    union { float f; unsigned i; } v; v.f = f;
    return (u16)((v.i + 0x7FFFu + ((v.i >> 16) & 1u)) >> 16);
}

// load 8 consecutive elements at element offset `off`, dtype per isf (fp32 vs bf16)
__device__ __forceinline__ sx8 load8(const void* p, bool isf, long off) {
    sx8 r;
    if (isf) {
        const float* f = (const float*)p + off;
        fx4 a = *(const fx4*)f, b = *(const fx4*)(f + 4);
        r[0] = (short)f2bf(a[0]); r[1] = (short)f2bf(a[1]);
        r[2] = (short)f2bf(a[2]); r[3] = (short)f2bf(a[3]);
        r[4] = (short)f2bf(b[0]); r[5] = (short)f2bf(b[1]);
        r[6] = (short)f2bf(b[2]); r[7] = (short)f2bf(b[3]);
    } else {
        r = *(const sx8*)((const u16*)p + off);
    }
    return r;
}
__device__ __forceinline__ float ldsc(const void* p, bool isf, long off) {
    return isf ? ((const float*)p)[off] : bf2f(((const u16*)p)[off]);
}

// ---------- dtype sniffer: fp32 data read as u16 has wild exponent fields ----------
__global__ void detect_dtype(const u16* __restrict__ x, int* __restrict__ flag) {
    int l = threadIdx.x;
    int bad = 0;
    for (int i = l; i < 4096; i += 64) {
        unsigned e = (x[i] >> 7) & 0xFF;
        if (e != 0 && (e < 64 || e > 191)) bad++;   // |v| outside [2^-63, 2^64]: never in bf16 N(0,1)
    }
    #pragma unroll
    for (int o = 32; o >= 1; o >>= 1) bad += __shfl_down(bad, o);
    if (l == 0) flag[0] = (bad > 16) ? 1 : 0;       // 1 = inputs are fp32
}

// ---------- universal MFMA GEMM: C[M,N](bf16) = A[M,K] @ B[K,N] (natural B!) ----------
// RAW bits: 1 = A is a raw input (dtype per flag), 2 = B+bias raw, 4 = resid raw.
// Block 256 = 4 waves (2x2). BM=128, BK=32. B staged via registers with in-LDS transpose
// (Bs row stride 36 u16: 2-way-max bank pattern, b64-aligned frag reads).
template<int BN, int RAW>
__global__ __launch_bounds__(256) void gemm(
    const void* __restrict__ A, long sA, int ldA,
    const void* __restrict__ B, long sB, int ldB,
    u16* __restrict__ C, long sC, int ldC,
    int K,
    const void* __restrict__ bias,
    const void* __restrict__ resid, long rofs,
    float scale, int relu,
    const int* __restrict__ flagp)
{
    constexpr int TM = 4;            // wave covers 64 rows
    constexpr int TN = BN / 32;      // wave covers BN/2 cols
    __shared__ u16 As[128 * 32];
    __shared__ u16 Bs[BN * 36];

    const int f = flagp[0];
    const bool af = (RAW & 1) && f, bfl = (RAW & 2) && f, rf = (RAW & 4) && f;

    const int tid = threadIdx.x, w = tid >> 6, lane = tid & 63;
    const int quad = lane >> 4, n16 = lane & 15;
    const int wrow = w >> 1, wcol = w & 1;
    const int m0 = blockIdx.y * 128, n0 = blockIdx.x * BN;
    const long z = blockIdx.z;
    const long za = z * sA, zb = z * sB;
    C += z * sC;

    fx4 acc[TM][TN] = {};

    const int arow = tid >> 1, acol = (tid & 1) * 16;
    int bk, bn;
    if (BN == 128) { bk = (tid & 15) * 2;  bn = ((tid >> 4) & 15) * 8; }
    else           { bk = tid & 31;        bn = ((tid >> 5) & 7) * 8;  }

    for (int k0 = 0; k0 < K; k0 += 32) {
        // global loads first (prefetch ahead of the barrier)
        long ab = za + (long)(m0 + arow) * ldA + k0 + acol;
        sx8 a0 = load8(A, af, ab), a1 = load8(A, af, ab + 8);
        sx8 r0, r1;
        long b0 = zb + (long)(k0 + bk) * ldB + n0 + bn;
        r0 = load8(B, bfl, b0);
        if (BN == 128) r1 = load8(B, bfl, b0 + ldB);

        __syncthreads();   // previous iteration's readers done
        *(sx8*)&As[arow * 32 + acol] = a0;
        *(sx8*)&As[arow * 32 + acol + 8] = a1;
        if (BN == 128) {
            #pragma unroll
            for (int j = 0; j < 8; ++j) {
                unsigned pk = (unsigned)(u16)r0[j] | ((unsigned)(u16)r1[j] << 16);
                *(unsigned*)&Bs[(bn + j) * 36 + bk] = pk;   // Bs[n][k], k-pair
            }
        } else {
            #pragma unroll
            for (int j = 0; j < 8; ++j) Bs[(bn + j) * 36 + bk] = (u16)r0[j];
        }
        __syncthreads();   // staging visible

        sx8 afr[TM], bfr[TN];
        #pragma unroll
        for (int r = 0; r < TM; ++r)
            afr[r] = *(const sx8*)&As[(wrow * 64 + r * 16 + n16) * 32 + quad * 8];
        #pragma unroll
        for (int c = 0; c < TN; ++c) {
            int n = wcol * (TN * 16) + c * 16 + n16;
            sx4 lo = *(const sx4*)&Bs[n * 36 + quad * 8];
            sx4 hi = *(const sx4*)&Bs[n * 36 + quad * 8 + 4];
            sx8 t;
            t[0] = lo[0]; t[1] = lo[1]; t[2] = lo[2]; t[3] = lo[3];
            t[4] = hi[0]; t[5] = hi[1]; t[6] = hi[2]; t[7] = hi[3];
            bfr[c] = t;
        }
        #pragma unroll
        for (int r = 0; r < TM; ++r)
            #pragma unroll
            for (int c = 0; c < TN; ++c)
                acc[r][c] = __builtin_amdgcn_mfma_f32_16x16x32_bf16(afr[r], bfr[c], acc[r][c], 0, 0, 0);
    }

    // epilogue: C/D layout col=lane&15, row=quad*4+reg (m89/m91-verified)
    #pragma unroll
    for (int r = 0; r < TM; ++r) {
        int row = m0 + wrow * 64 + r * 16 + quad * 4;
        #pragma unroll
        for (int c = 0; c < TN; ++c) {
            int col = n0 + wcol * (TN * 16) + c * 16 + n16;
            float bv = bias ? ldsc(bias, bfl, col) : 0.f;
            #pragma unroll
            for (int g = 0; g < 4; ++g) {
                long idx = (long)(row + g) * ldC + col;
                float xv = acc[r][c][g] * scale + bv;
                if (resid) xv += ldsc(resid, rf, rofs + idx);
                if (relu) xv = fmaxf(xv, 0.f);
                C[idx] = f2bf(xv);
            }
        }
    }
}

// ---------- softmax over head axis (16), in-place; hstride = LCH*1024 ----------
__global__ __launch_bounds__(256) void softmax_h(
    u16* __restrict__ SP, const int* __restrict__ mask, int hstride)
{
    int idx = blockIdx.x * 256 + threadIdx.x;
    bool mz = (mask[idx] == 0);
    float v[16], mx = -1e30f;
    #pragma unroll
    for (int h = 0; h < 16; ++h) {
        float s = mz ? -1e-12f : bf2f(SP[(long)h * hstride + idx]);
        v[h] = s; mx = fmaxf(mx, s);
    }
    float sum = 0.f;
    #pragma unroll
    for (int h = 0; h < 16; ++h) { v[h] = __expf(v[h] - mx); sum += v[h]; }
    float inv = 1.f / sum;
    #pragma unroll
    for (int h = 0; h < 16; ++h)
        SP[(long)h * hstride + idx] = f2bf(v[h] * inv);
}

// ---------- LayerNorm (ddof=1, /(std+eps)); in = bf16; g/be raw if GRAW; out raw if ORAW ----------
template<int GRAW, int ORAW>
__global__ __launch_bounds__(256) void layernorm_row(
    const u16* __restrict__ in, const void* __restrict__ g,
    const void* __restrict__ be, void* __restrict__ out,
    const int* __restrict__ flagp)
{
    const int f = flagp[0];
    const bool gf = GRAW && f, of = ORAW && f;
    int wave = threadIdx.x >> 6, lane = threadIdx.x & 63;
    long row = (long)blockIdx.x * 4 + wave;
    const u16* p = in + row * 1024 + lane * 16;

    float x[16];
    uint4 a = ((const uint4*)p)[0], b = ((const uint4*)p)[1];
    {
        unsigned u;
        u = a.x; x[0] = bf2f(u & 0xffff);  x[1] = bf2f(u >> 16);
        u = a.y; x[2] = bf2f(u & 0xffff);  x[3] = bf2f(u >> 16);
        u = a.z; x[4] = bf2f(u & 0xffff);  x[5] = bf2f(u >> 16);
        u = a.w; x[6] = bf2f(u & 0xffff);  x[7] = bf2f(u >> 16);
        u = b.x; x[8] = bf2f(u & 0xffff);  x[9] = bf2f(u >> 16);
        u = b.y; x[10] = bf2f(u & 0xffff); x[11] = bf2f(u >> 16);
        u = b.z; x[12] = bf2f(u & 0xffff); x[13] = bf2f(u >> 16);
        u = b.w; x[14] = bf2f(u & 0xffff); x[15] = bf2f(u >> 16);
    }
    float s = 0.f, ss = 0.f;
    #pragma unroll
    for (int i = 0; i < 16; ++i) { s += x[i]; ss += x[i] * x[i]; }
    #pragma unroll
    for (int o = 32; o >= 1; o >>= 1) { s += __shfl_down(s, o); ss += __shfl_down(ss, o); }
    s = __shfl(s, 0); ss = __shfl(ss, 0);
    float mean = s * (1.f / 1024.f);
    float var  = fmaxf((ss - 1024.f * mean * mean) * (1.f / 1023.f), 0.f);  // ddof=1
    float rinv = 1.f / (sqrtf(var) + 1e-12f);                               // /(std+eps)

    int col = lane * 16;
    if (of) {
        float* ov = (float*)out + row * 1024 + col;
        #pragma unroll
        for (int i = 0; i < 16; ++i)
            ov[i] = ldsc(g, gf, col + i) * ((x[i] - mean) * rinv) + ldsc(be, gf, col + i);
    } else {
        u16* ov = (u16*)out + row * 1024 + col;
        #pragma unroll
        for (int i = 0; i < 16; ++i)
            ov[i] = f2bf(ldsc(g, gf, col + i) * ((x[i] - mean) * rinv) + ldsc(be, gf, col + i));
    }
}

// ---------- launch ----------
// ws layout (tier by ws_size): qb[0,16) kb[16,32) vb[32,48) sp[48,48+S)
// ao_b[+2) t0[+16) flag[+4B];  x1 overlays qb, fh(32MB) overlays kb+vb.
// big tier (ws>=99MB): S=32, LCH=1024, peak 98MB. small: S=8, LCH=256, peak 74MB.
extern "C" void kernel_launch(void* const* d_in, const int* in_sizes, int n_in,
                              void* d_out, int out_size, void* d_ws, size_t ws_size,
                              hipStream_t stream)
{
    const void* x  = d_in[0];
    const int* mask = (const int*)d_in[1];
    const void* wq = d_in[2];  const void* bq = d_in[3];
    const void* wk = d_in[4];  const void* bk = d_in[5];
    const void* wv = d_in[6];  const void* bv = d_in[7];
    const void* wc = d_in[8];  const void* bc = d_in[9];
    const void* g1 = d_in[10]; const void* be1 = d_in[11];
    const void* w1 = d_in[12]; const void* b1 = d_in[13];
    const void* w2 = d_in[14]; const void* b2 = d_in[15];
    const void* g2 = d_in[16]; const void* be2 = d_in[17];

    char* ws = (char*)d_ws;
    const long MB = 1 << 20;
    const int big = ws_size >= (size_t)(99 * MB);
    const int LCH = big ? 1024 : 256;         // attention l-chunk rows
    const long spMB = big ? 32 : 8;

    u16* qb  = (u16*)(ws + 0 * MB);
    u16* kb  = (u16*)(ws + 16 * MB);
    u16* vb  = (u16*)(ws + 32 * MB);
    u16* sp  = (u16*)(ws + 48 * MB);
    u16* aob = (u16*)(ws + (48 + spMB) * MB);
    u16* t0  = (u16*)(ws + (50 + spMB) * MB);
    u16* x1  = qb;                            // overlay: qb dead after attention
    u16* fh  = kb;                            // overlay: kb+vb dead after attention (32 MB)
    int* flagp = (int*)(ws + (66 + spMB) * MB);

    dim3 blk(256);
    const long M1 = 1048576;

    detect_dtype<<<1, 64, 0, stream>>>((const u16*)x, flagp);

    // QKV projections: [8192,1024] @ [1024,1024] + bias
    gemm<128, 3><<<dim3(8, 64, 1), blk, 0, stream>>>(
        x, 0, 1024, wq, 0, 1024, qb, 0, 1024, 1024, bq, nullptr, 0, 1.f, 0, flagp);
    gemm<128, 3><<<dim3(8, 64, 1), blk, 0, stream>>>(
        x, 0, 1024, wk, 0, 1024, kb, 0, 1024, 1024, bk, nullptr, 0, 1.f, 0, flagp);
    gemm<128, 3><<<dim3(8, 64, 1), blk, 0, stream>>>(
        x, 0, 1024, wv, 0, 1024, vb, 0, 1024, 1024, bv, nullptr, 0, 1.f, 0, flagp);

    for (int b = 0; b < 8; ++b) {
        for (int ch = 0; ch < 1024 / LCH; ++ch) {
            long l0 = (long)ch * LCH;
            // S_h = (Q_h @ K_t_h)/8 : A=Q_h[l0:,64] (ldA=64), B=K_t_h [64,1024] natural
            gemm<128, 0><<<dim3(8, LCH / 128, 16), blk, 0, stream>>>(
                qb + b * M1 + l0 * 64, 65536, 64,
                kb + b * M1, 65536, 1024,
                sp, (long)LCH * 1024, 1024, 64,
                nullptr, nullptr, 0, 0.125f, 0, flagp);
            softmax_h<<<dim3(LCH * 1024 / 256), blk, 0, stream>>>(
                sp, mask + b * M1 + l0 * 1024, LCH * 1024);
            // O_h = P_h @ V_h : B=V_h [1024,64] natural
            gemm<64, 0><<<dim3(1, LCH / 128, 16), blk, 0, stream>>>(
                sp, (long)LCH * 1024, 1024,
                vb + b * M1, 65536, 64,
                aob + l0 * 64, 65536, 64, 1024,
                nullptr, nullptr, 0, 1.f, 0, flagp);
        }
        // out-proj + bias + residual x[b] -> t0[b]
        gemm<128, 6><<<dim3(8, 8, 1), blk, 0, stream>>>(
            aob, 0, 1024, wc, 0, 1024, t0 + b * M1, 0, 1024, 1024,
            bc, x, b * M1, 1.f, 0, flagp);
    }

    layernorm_row<1, 0><<<dim3(2048), blk, 0, stream>>>(t0, g1, be1, x1, flagp);

    // FFN, 2 row-chunks of 4096 (fh = 32 MB overlay)
    for (int c2 = 0; c2 < 2; ++c2) {
        long r0 = (long)c2 * 4096;
        gemm<128, 2><<<dim3(32, 32, 1), blk, 0, stream>>>(
            x1 + r0 * 1024, 0, 1024, w1, 0, 4096, fh, 0, 4096, 1024,
            b1, nullptr, 0, 1.f, 1, flagp);
        gemm<128, 2><<<dim3(8, 32, 1), blk, 0, stream>>>(
            fh, 0, 4096, w2, 0, 1024, t0 + r0 * 1024, 0, 1024, 4096,
            b2, x1 + r0 * 1024, 0, 1.f, 0, flagp);
    }

    layernorm_row<1, 1><<<dim3(2048), blk, 0, stream>>>(t0, g2, be2, d_out, flagp);
}

// Round 5
// 1380.122 us; speedup vs baseline: 1.6165x; 1.6165x over previous
//
#include <hip/hip_runtime.h>
#include <stdint.h>

typedef unsigned short u16;
typedef __attribute__((ext_vector_type(8))) short sx8;   // 8 bf16 (4 VGPRs) — MFMA A/B frag
typedef __attribute__((ext_vector_type(4))) float fx4;   // MFMA C/D frag

__device__ __forceinline__ float bf2f(u16 u) {
    union { unsigned i; float f; } v; v.i = ((unsigned)u) << 16; return v.f;
}
__device__ __forceinline__ u16 f2bf(float f) {
    union { float f; unsigned i; } v; v.f = f;
    return (u16)((v.i + 0x7FFFu + ((v.i >> 16) & 1u)) >> 16);
}

#define GLDS(gp, lp) \
    __builtin_amdgcn_global_load_lds((const __attribute__((address_space(1))) void*)(gp), \
                                     (__attribute__((address_space(3))) void*)(lp), 16, 0, 0)

// ---------- m97-style MFMA GEMM: C[M,N] = A[M,K] @ BT[N,K]^T, all bf16 ----------
// 256 thr = 4 waves (2x2); BM=128, BK=32; per-wave 4xTN grid of 16x16x32 mfma.
// bias: packed bf16, offset bz*z. resid: fp32 or bf16 per residF32, at rofs+idx.
template<int BN>
__global__ __launch_bounds__(256) void gemm_bt(
    const u16* __restrict__ A, long sA, int ldA,
    const u16* __restrict__ BT, long sBT, int ldBT,
    u16* __restrict__ C, long sC, int ldC,
    int K,
    const u16* __restrict__ bias, int bz,
    const void* __restrict__ resid, int residF32, long rofs,
    float scale, int relu)
{
    constexpr int BK = 32;
    constexpr int TM = 4;            // 4*16 = 64 rows per wave, 2 wrows = 128
    constexpr int TN = BN / 32;
    constexpr int AI = 2;            // 128*32*2B / (4 waves * 1KB)
    constexpr int BI = BN / 64;

    __shared__ __align__(16) u16 As[128 * BK];
    __shared__ __align__(16) u16 Bs[BN * BK];

    const int tid  = threadIdx.x;
    const int w    = tid >> 6;
    const int lane = tid & 63;
    const int quad = lane >> 4;
    const int n16  = lane & 15;
    const int wrow = w >> 1, wcol = w & 1;
    const int m0 = blockIdx.y * 128, n0 = blockIdx.x * BN;
    const long z = blockIdx.z;
    A  += z * sA;
    BT += z * sBT;
    C  += z * sC;

    fx4 acc[TM][TN] = {};

    for (int k0 = 0; k0 < K; k0 += BK) {
        #pragma unroll
        for (int i = 0; i < AI; ++i) {
            unsigned base = (unsigned)(w * AI + i) * 1024u;   // wave-uniform LDS byte base
            unsigned off  = base + (unsigned)lane * 16u;
            unsigned row  = off >> 6;                          // 64B per row of 32 bf16
            unsigned col  = (off & 63u) >> 1;
            GLDS(A + (long)(m0 + row) * ldA + k0 + col, (char*)As + base);
        }
        #pragma unroll
        for (int i = 0; i < BI; ++i) {
            unsigned base = (unsigned)(w * BI + i) * 1024u;
            unsigned off  = base + (unsigned)lane * 16u;
            unsigned row  = off >> 6;
            unsigned col  = (off & 63u) >> 1;
            GLDS(BT + (long)(n0 + row) * ldBT + k0 + col, (char*)Bs + base);
        }
        __syncthreads();

        sx8 af[TM], bfr[TN];
        #pragma unroll
        for (int r = 0; r < TM; ++r)
            af[r] = *(const sx8*)&As[(wrow * 64 + r * 16 + n16) * BK + quad * 8];
        #pragma unroll
        for (int c = 0; c < TN; ++c)
            bfr[c] = *(const sx8*)&Bs[(wcol * (TN * 16) + c * 16 + n16) * BK + quad * 8];
        #pragma unroll
        for (int r = 0; r < TM; ++r)
            #pragma unroll
            for (int c = 0; c < TN; ++c)
                acc[r][c] = __builtin_amdgcn_mfma_f32_16x16x32_bf16(af[r], bfr[c], acc[r][c], 0, 0, 0);
        __syncthreads();
    }

    // epilogue: C/D layout col=lane&15, row=quad*4+reg (m89/m91; round-3 verified)
    #pragma unroll
    for (int r = 0; r < TM; ++r) {
        int row = m0 + wrow * 64 + r * 16 + quad * 4;
        #pragma unroll
        for (int c = 0; c < TN; ++c) {
            int col = n0 + wcol * (TN * 16) + c * 16 + n16;
            float bv = bias ? bf2f(bias[bz * (int)z + col]) : 0.f;
            #pragma unroll
            for (int g = 0; g < 4; ++g) {
                long idx = (long)(row + g) * ldC + col;
                float xv = acc[r][c][g] * scale + bv;
                if (resid)
                    xv += residF32 ? ((const float*)resid)[rofs + idx]
                                   : bf2f(((const u16*)resid)[rofs + idx]);
                if (relu) xv = fmaxf(xv, 0.f);
                C[idx] = f2bf(xv);
            }
        }
    }
}

// ---------- fp32 -> bf16 elementwise (x conversion) ----------
__global__ __launch_bounds__(256) void convert_f2b(
    const float* __restrict__ in, u16* __restrict__ out)
{
    long i = ((long)blockIdx.x * 256 + threadIdx.x) * 4;
    fx4 v = *(const fx4*)(in + i);
    uint2 o;
    o.x = (unsigned)f2bf(v[0]) | ((unsigned)f2bf(v[1]) << 16);
    o.y = (unsigned)f2bf(v[2]) | ((unsigned)f2bf(v[3]) << 16);
    *(uint2*)(out + i) = o;
}

// ---------- fp32 [R][C] -> bf16 transposed [C][R] ----------
__global__ __launch_bounds__(256) void transpose_f2b(
    const float* __restrict__ in, u16* __restrict__ out, int R, int C)
{
    __shared__ float t[32][33];
    int c0 = blockIdx.x * 32, r0 = blockIdx.y * 32;
    int tx = threadIdx.x & 31, ty = threadIdx.x >> 5;
    #pragma unroll
    for (int i = 0; i < 4; ++i)
        t[ty + i * 8][tx] = in[(long)(r0 + ty + i * 8) * C + c0 + tx];
    __syncthreads();
    #pragma unroll
    for (int i = 0; i < 4; ++i)
        out[(long)(c0 + ty + i * 8) * R + r0 + tx] = f2bf(t[tx][ty + i * 8]);
}

// ---------- bf16 batched transpose: out[z][c][r] = in[z][r][c] ----------
__global__ __launch_bounds__(256) void transpose_bf(
    const u16* __restrict__ in, u16* __restrict__ out, int R, int C)
{
    __shared__ u16 t[32][33];
    long zoff = (long)blockIdx.z * (long)R * (long)C;
    in += zoff; out += zoff;
    int c0 = blockIdx.x * 32, r0 = blockIdx.y * 32;
    int tx = threadIdx.x & 31, ty = threadIdx.x >> 5;
    #pragma unroll
    for (int i = 0; i < 4; ++i)
        t[ty + i * 8][tx] = in[(long)(r0 + ty + i * 8) * C + c0 + tx];
    __syncthreads();
    #pragma unroll
    for (int i = 0; i < 4; ++i)
        out[(long)(c0 + ty + i * 8) * R + r0 + tx] = t[tx][ty + i * 8];
}

// ---------- pack all biases fp32 -> bf16 [bq|bk|bv|bc|b1|b2] = 9216 elems ----------
__global__ __launch_bounds__(256) void pack_bias(
    const float* bq, const float* bk, const float* bv, const float* bc,
    const float* b1, const float* b2, u16* __restrict__ out)
{
    int i = blockIdx.x * 256 + threadIdx.x;
    float v;
    if      (i < 1024) v = bq[i];
    else if (i < 2048) v = bk[i - 1024];
    else if (i < 3072) v = bv[i - 2048];
    else if (i < 4096) v = bc[i - 3072];
    else if (i < 8192) v = b1[i - 4096];
    else               v = b2[i - 8192];
    out[i] = f2bf(v);
}

// ---------- softmax over head axis (16), in-place; hstride elems per head ----------
__global__ __launch_bounds__(256) void softmax_h(
    u16* __restrict__ SP, const int* __restrict__ mask, int hstride)
{
    int idx = blockIdx.x * 256 + threadIdx.x;
    bool mz = (mask[idx] == 0);
    float v[16], mx = -1e30f;
    #pragma unroll
    for (int h = 0; h < 16; ++h) {
        float s = mz ? -1e-12f : bf2f(SP[(long)h * hstride + idx]);
        v[h] = s; mx = fmaxf(mx, s);
    }
    float sum = 0.f;
    #pragma unroll
    for (int h = 0; h < 16; ++h) { v[h] = __expf(v[h] - mx); sum += v[h]; }
    float inv = 1.f / sum;
    #pragma unroll
    for (int h = 0; h < 16; ++h)
        SP[(long)h * hstride + idx] = f2bf(v[h] * inv);
}

// ---------- LayerNorm (ddof=1, /(std+eps)); in bf16; g/be fp32; out bf16 or fp32 ----------
__global__ __launch_bounds__(256) void layernorm_row(
    const u16* __restrict__ in, const float* __restrict__ g,
    const float* __restrict__ be, void* __restrict__ out, int outF32)
{
    int wave = threadIdx.x >> 6, lane = threadIdx.x & 63;
    long row = (long)blockIdx.x * 4 + wave;
    const u16* p = in + row * 1024 + lane * 16;

    float x[16];
    uint4 a = ((const uint4*)p)[0], b = ((const uint4*)p)[1];
    {
        unsigned u;
        u = a.x; x[0] = bf2f(u & 0xffff);  x[1] = bf2f(u >> 16);
        u = a.y; x[2] = bf2f(u & 0xffff);  x[3] = bf2f(u >> 16);
        u = a.z; x[4] = bf2f(u & 0xffff);  x[5] = bf2f(u >> 16);
        u = a.w; x[6] = bf2f(u & 0xffff);  x[7] = bf2f(u >> 16);
        u = b.x; x[8] = bf2f(u & 0xffff);  x[9] = bf2f(u >> 16);
        u = b.y; x[10] = bf2f(u & 0xffff); x[11] = bf2f(u >> 16);
        u = b.z; x[12] = bf2f(u & 0xffff); x[13] = bf2f(u >> 16);
        u = b.w; x[14] = bf2f(u & 0xffff); x[15] = bf2f(u >> 16);
    }
    float s = 0.f, ss = 0.f;
    #pragma unroll
    for (int i = 0; i < 16; ++i) { s += x[i]; ss += x[i] * x[i]; }
    #pragma unroll
    for (int o = 32; o >= 1; o >>= 1) { s += __shfl_down(s, o); ss += __shfl_down(ss, o); }
    s = __shfl(s, 0); ss = __shfl(ss, 0);
    float mean = s * (1.f / 1024.f);
    float var  = fmaxf((ss - 1024.f * mean * mean) * (1.f / 1023.f), 0.f);  // ddof=1
    float rinv = 1.f / (sqrtf(var) + 1e-12f);                               // /(std+eps)

    int col = lane * 16;
    if (outF32) {
        float* ov = (float*)out + row * 1024 + col;
        #pragma unroll
        for (int i = 0; i < 16; ++i)
            ov[i] = g[col + i] * ((x[i] - mean) * rinv) + be[col + i];
    } else {
        u16* ov = (u16*)out + row * 1024 + col;
        #pragma unroll
        for (int i = 0; i < 16; ++i)
            ov[i] = f2bf(g[col + i] * ((x[i] - mean) * rinv) + be[col + i]);
    }
}

// ---------- launch ----------
// ws map (MB, peak 96 + 18KB bias — fits the 98MB proven in round 3):
//  [0,16)  xb (bf16 x)      -> ao (attention out, HEAD-MAJOR flat; xb dead after QKV)
//  [16,22) wqkvT [3][1024][1024]
//  [22,24) wcT
//  [24,40) qb               -> t0/x1 (out-proj writes here; LN1 in-place)
//  [40,56) kb  -> vt        -> w1T[40,48)+w2T[48,56) (post-attention)
//  [56,72) vb  -> sp (LCH=512) -> fh[56,88) lower
//  [72,88) kt               -> fh upper
//  [88,96) pre2 (FFN2 out, 4096-row chunks)
//  [96, +18KB) packed biases
extern "C" void kernel_launch(void* const* d_in, const int* in_sizes, int n_in,
                              void* d_out, int out_size, void* d_ws, size_t ws_size,
                              hipStream_t stream)
{
    const float* xf  = (const float*)d_in[0];
    const int* mask  = (const int*)d_in[1];
    const float* wq = (const float*)d_in[2];  const float* bq = (const float*)d_in[3];
    const float* wk = (const float*)d_in[4];  const float* bk = (const float*)d_in[5];
    const float* wv = (const float*)d_in[6];  const float* bv = (const float*)d_in[7];
    const float* wc = (const float*)d_in[8];  const float* bc = (const float*)d_in[9];
    const float* g1 = (const float*)d_in[10]; const float* be1 = (const float*)d_in[11];
    const float* w1 = (const float*)d_in[12]; const float* b1 = (const float*)d_in[13];
    const float* w2 = (const float*)d_in[14]; const float* b2 = (const float*)d_in[15];
    const float* g2 = (const float*)d_in[16]; const float* be2 = (const float*)d_in[17];

    char* ws = (char*)d_ws;
    const long MB = 1 << 20;
    u16* xb    = (u16*)(ws + 0 * MB);      // -> ao
    u16* wqkvT = (u16*)(ws + 16 * MB);
    u16* wcT   = (u16*)(ws + 22 * MB);
    u16* qb    = (u16*)(ws + 24 * MB);     // -> t0/x1
    u16* kb    = (u16*)(ws + 40 * MB);     // -> vt -> w1T/w2T
    u16* vb    = (u16*)(ws + 56 * MB);     // -> sp -> fh
    u16* kt    = (u16*)(ws + 72 * MB);
    u16* pre2  = (u16*)(ws + 88 * MB);
    u16* biasp = (u16*)(ws + 96 * MB);
    u16* ao  = xb;
    u16* vt  = kb;
    u16* sp  = vb;
    u16* t0  = qb;                          // == x1 (LN1 in-place)
    u16* w1T = (u16*)(ws + 40 * MB);
    u16* w2T = (u16*)(ws + 48 * MB);
    u16* fh  = (u16*)(ws + 56 * MB);

    dim3 blk(256);
    const long M1 = 1048576;

    // ---- phase 0: conversions ----
    convert_f2b<<<dim3(8192), blk, 0, stream>>>(xf, xb);
    transpose_f2b<<<dim3(32, 32), blk, 0, stream>>>(wq, wqkvT, 1024, 1024);
    transpose_f2b<<<dim3(32, 32), blk, 0, stream>>>(wk, wqkvT + M1, 1024, 1024);
    transpose_f2b<<<dim3(32, 32), blk, 0, stream>>>(wv, wqkvT + 2 * M1, 1024, 1024);
    transpose_f2b<<<dim3(32, 32), blk, 0, stream>>>(wc, wcT, 1024, 1024);
    pack_bias<<<dim3(36), blk, 0, stream>>>(bq, bk, bv, bc, b1, b2, biasp);

    // ---- phase 1: fused QKV  [8192,1024] @ 3x[1024,1024] ----
    gemm_bt<128><<<dim3(8, 64, 3), blk, 0, stream>>>(
        xb, 0, 1024, wqkvT, M1, 1024, qb, 8 * M1, 1024, 1024,
        biasp, 1024, nullptr, 0, 0, 1.f, 0);

    // ---- phase 2: per-head transposes (contiguous head blocks, reshape quirk) ----
    transpose_bf<<<dim3(32, 2, 128), blk, 0, stream>>>(kb, kt, 64, 1024);   // K^T_h -> kt [1024][64]
    transpose_bf<<<dim3(2, 32, 128), blk, 0, stream>>>(vb, vt, 1024, 64);   // V_h -> vt [64][1024]

    // ---- phase 3: attention, per (b, l-chunk of 512) ----
    for (int b = 0; b < 8; ++b) {
        for (int ch = 0; ch < 2; ++ch) {
            long l0 = (long)ch * 512;
            // S_h = (Q_h @ K^T_h)/8 : M=512,N=1024,K=64, z=16 heads
            gemm_bt<128><<<dim3(8, 4, 16), blk, 0, stream>>>(
                qb + b * M1 + l0 * 64, 65536, 64,
                kt + b * M1, 65536, 64,
                sp, 524288, 1024, 64,
                nullptr, 0, nullptr, 0, 0, 0.125f, 0);
            softmax_h<<<dim3(2048), blk, 0, stream>>>(
                sp, mask + b * M1 + l0 * 1024, 524288);
            // O_h = P_h @ V_h : M=512,N=64,K=1024.
            // CRITICAL (round-4 bug): out.reshape(B,L,D) flattens [H][L][DT] head-major.
            // Store head-major flat: C = ao + b*M1 + l0*64 + h*65536 + l_local*64 + d.
            gemm_bt<64><<<dim3(1, 4, 16), blk, 0, stream>>>(
                sp, 524288, 1024,
                vt + b * M1, 65536, 1024,
                ao + b * M1 + l0 * 64, 65536, 64, 1024,
                nullptr, 0, nullptr, 0, 0, 1.f, 0);
        }
    }

    // ---- phase 4: out-proj (+bias+resid x) over all 8192 rows -> t0 (qb region) ----
    // ao read as [8192][1024] row-major == the quirky reshape view.
    gemm_bt<128><<<dim3(8, 64, 1), blk, 0, stream>>>(
        ao, 0, 1024, wcT, 0, 1024, t0, 0, 1024, 1024,
        biasp + 3072, 0, xf, 1, 0, 1.f, 0);
    layernorm_row<<<dim3(2048), blk, 0, stream>>>(t0, g1, be1, t0, 0);  // in-place -> x1

    // ---- phase 5: FFN weight transposes into dead vt region ----
    transpose_f2b<<<dim3(128, 32), blk, 0, stream>>>(w1, w1T, 1024, 4096);
    transpose_f2b<<<dim3(32, 128), blk, 0, stream>>>(w2, w2T, 4096, 1024);

    // ---- phase 6: FFN + LN2, 2 chunks of 4096 rows ----
    for (int c = 0; c < 2; ++c) {
        long r0 = (long)c * 4096 * 1024;
        gemm_bt<128><<<dim3(32, 32, 1), blk, 0, stream>>>(
            t0 + r0, 0, 1024, w1T, 0, 1024, fh, 0, 4096, 1024,
            biasp + 4096, 0, nullptr, 0, 0, 1.f, 1);
        gemm_bt<128><<<dim3(8, 32, 1), blk, 0, stream>>>(
            fh, 0, 4096, w2T, 0, 4096, pre2, 0, 1024, 4096,
            biasp + 8192, 0, t0 + r0, 0, 0, 1.f, 0);
        layernorm_row<<<dim3(1024), blk, 0, stream>>>(
            pre2, g2, be2, (float*)d_out + r0, 1);
    }
}

// Round 7
// 1116.387 us; speedup vs baseline: 1.9984x; 1.2362x over previous
//
#include <hip/hip_runtime.h>
#include <stdint.h>

typedef unsigned short u16;
typedef __attribute__((ext_vector_type(8))) short sx8;   // 8 bf16 (4 VGPRs) — MFMA A/B frag
typedef __attribute__((ext_vector_type(4))) float fx4;   // MFMA C/D frag

__device__ __forceinline__ float bf2f(u16 u) {
    union { unsigned i; float f; } v; v.i = ((unsigned)u) << 16; return v.f;
}
__device__ __forceinline__ u16 f2bf(float f) {
    union { float f; unsigned i; } v; v.f = f;
    return (u16)((v.i + 0x7FFFu + ((v.i >> 16) & 1u)) >> 16);
}
#define MFMA(a, b, c) __builtin_amdgcn_mfma_f32_16x16x32_bf16((a), (b), (c), 0, 0, 0)

#define GLDS(gp, lp) \
    __builtin_amdgcn_global_load_lds((const __attribute__((address_space(1))) void*)(gp), \
                                     (__attribute__((address_space(3))) void*)(lp), 16, 0, 0)

// ---------- m97-style MFMA GEMM: C[M,N] = A[M,K] @ BT[N,K]^T, all bf16 ----------
template<int BN>
__global__ __launch_bounds__(256) void gemm_bt(
    const u16* __restrict__ A, long sA, int ldA,
    const u16* __restrict__ BT, long sBT, int ldBT,
    u16* __restrict__ C, long sC, int ldC,
    int K,
    const u16* __restrict__ bias, int bz,
    const void* __restrict__ resid, int residF32, long rofs,
    float scale, int relu)
{
    constexpr int BK = 32;
    constexpr int TM = 4;
    constexpr int TN = BN / 32;
    constexpr int AI = 2;
    constexpr int BI = BN / 64;

    __shared__ __align__(16) u16 As[128 * BK];
    __shared__ __align__(16) u16 Bs[BN * BK];

    const int tid  = threadIdx.x;
    const int w    = tid >> 6;
    const int lane = tid & 63;
    const int quad = lane >> 4;
    const int n16  = lane & 15;
    const int wrow = w >> 1, wcol = w & 1;
    const int m0 = blockIdx.y * 128, n0 = blockIdx.x * BN;
    const long z = blockIdx.z;
    A  += z * sA;
    BT += z * sBT;
    C  += z * sC;

    fx4 acc[TM][TN] = {};

    for (int k0 = 0; k0 < K; k0 += BK) {
        #pragma unroll
        for (int i = 0; i < AI; ++i) {
            unsigned base = (unsigned)(w * AI + i) * 1024u;
            unsigned off  = base + (unsigned)lane * 16u;
            unsigned row  = off >> 6;
            unsigned col  = (off & 63u) >> 1;
            GLDS(A + (long)(m0 + row) * ldA + k0 + col, (char*)As + base);
        }
        #pragma unroll
        for (int i = 0; i < BI; ++i) {
            unsigned base = (unsigned)(w * BI + i) * 1024u;
            unsigned off  = base + (unsigned)lane * 16u;
            unsigned row  = off >> 6;
            unsigned col  = (off & 63u) >> 1;
            GLDS(BT + (long)(n0 + row) * ldBT + k0 + col, (char*)Bs + base);
        }
        __syncthreads();

        sx8 af[TM], bfr[TN];
        #pragma unroll
        for (int r = 0; r < TM; ++r)
            af[r] = *(const sx8*)&As[(wrow * 64 + r * 16 + n16) * BK + quad * 8];
        #pragma unroll
        for (int c = 0; c < TN; ++c)
            bfr[c] = *(const sx8*)&Bs[(wcol * (TN * 16) + c * 16 + n16) * BK + quad * 8];
        #pragma unroll
        for (int r = 0; r < TM; ++r)
            #pragma unroll
            for (int c = 0; c < TN; ++c)
                acc[r][c] = MFMA(af[r], bfr[c], acc[r][c]);
        __syncthreads();
    }

    #pragma unroll
    for (int r = 0; r < TM; ++r) {
        int row = m0 + wrow * 64 + r * 16 + quad * 4;
        #pragma unroll
        for (int c = 0; c < TN; ++c) {
            int col = n0 + wcol * (TN * 16) + c * 16 + n16;
            float bv = bias ? bf2f(bias[bz * (int)z + col]) : 0.f;
            #pragma unroll
            for (int g = 0; g < 4; ++g) {
                long idx = (long)(row + g) * ldC + col;
                float xv = acc[r][c][g] * scale + bv;
                if (resid)
                    xv += residF32 ? ((const float*)resid)[rofs + idx]
                                   : bf2f(((const u16*)resid)[rofs + idx]);
                if (relu) xv = fmaxf(xv, 0.f);
                C[idx] = f2bf(xv);
            }
        }
    }
}

// ---------- fused attention: S=Q@Kt/8, head-softmax, O=PV ----------
// QUIRK-FAITHFUL: kt[z=(b,h)][m][d] is the pre-transposed reshape-view K_t
// (K_t_h[d][m] = k_flat[h*65536 + d*1024 + m]), exactly as rounds 3/5 used.
// qb [b][16h][1024 l][64 d] flat view; vt [local b][16h][64 d][1024 m];
// ao [b][16h][1024 l][64 d]. Block=(l-tile 16, local b). 4 waves x 4 heads.
// Ss LDS [16h][16l][40m] bf16.
__global__ __launch_bounds__(256) void attn_fused(
    const u16* __restrict__ qb, const u16* __restrict__ kt,
    const u16* __restrict__ vt, const int* __restrict__ mask,
    u16* __restrict__ ao)
{
    __shared__ u16 Ss[16 * 648];

    const int tid = threadIdx.x, w = tid >> 6, lane = tid & 63;
    const int quad = lane >> 4, n16 = lane & 15;
    const int l0 = blockIdx.x * 16;
    const long bo = (long)blockIdx.y * 1048576;

    // resident Q A-frags for this wave's 4 heads
    sx8 qf[4][2];
    #pragma unroll
    for (int i = 0; i < 4; ++i) {
        const u16* qp = qb + bo + (w * 4 + i) * 65536 + (l0 + n16) * 64 + quad * 8;
        qf[i][0] = *(const sx8*)qp;
        qf[i][1] = *(const sx8*)(qp + 32);
    }

    fx4 of[4][4] = {};   // O accumulators [head][d-tile]

    for (int mt = 0; mt < 32; ++mt) {
        const int m0 = mt * 32;
        // ---- S = (Q @ Kt)/8 : B-frag rows from kt[m][d] (d contiguous) ----
        #pragma unroll
        for (int i = 0; i < 4; ++i) {
            const int h = w * 4 + i;
            const u16* kp = kt + bo + h * 65536 + (long)m0 * 64;
            #pragma unroll
            for (int nt = 0; nt < 2; ++nt) {
                const u16* kr = kp + (nt * 16 + n16) * 64 + quad * 8;
                fx4 s = {};
                s = MFMA(qf[i][0], *(const sx8*)kr, s);
                s = MFMA(qf[i][1], *(const sx8*)(kr + 32), s);
                #pragma unroll
                for (int r = 0; r < 4; ++r)
                    Ss[h * 648 + (quad * 4 + r) * 40 + nt * 16 + n16] = f2bf(s[r] * 0.125f);
            }
        }
        __syncthreads();
        // ---- softmax over the 16 heads, pointwise in (l,m) ----
        #pragma unroll
        for (int j = 0; j < 2; ++j) {
            const int p = tid + 256 * j;
            const int l = p >> 5, m = p & 31;
            const bool mz = (mask[bo + (long)(l0 + l) * 1024 + m0 + m] == 0);
            u16* col = &Ss[l * 40 + m];
            float v[16], mx = -1e30f;
            #pragma unroll
            for (int h = 0; h < 16; ++h) {
                float s = mz ? -1e-12f : bf2f(col[h * 648]);
                v[h] = s; mx = fmaxf(mx, s);
            }
            float sum = 0.f;
            #pragma unroll
            for (int h = 0; h < 16; ++h) { v[h] = __expf(v[h] - mx); sum += v[h]; }
            float inv = 1.f / sum;
            #pragma unroll
            for (int h = 0; h < 16; ++h) col[h * 648] = f2bf(v[h] * inv);
        }
        __syncthreads();
        // ---- O += P @ V (A-frag from Ss, B-frag from vt, m contiguous) ----
        #pragma unroll
        for (int i = 0; i < 4; ++i) {
            const int h = w * 4 + i;
            sx8 af = *(const sx8*)&Ss[h * 648 + n16 * 40 + quad * 8];
            const u16* vp = vt + bo + h * 65536 + (long)n16 * 1024 + m0 + quad * 8;
            #pragma unroll
            for (int dt = 0; dt < 4; ++dt)
                of[i][dt] = MFMA(af, *(const sx8*)(vp + dt * 16384), of[i][dt]);
        }
        __syncthreads();
    }

    // ---- epilogue: head-major flat store ----
    #pragma unroll
    for (int i = 0; i < 4; ++i) {
        const int h = w * 4 + i;
        #pragma unroll
        for (int dt = 0; dt < 4; ++dt)
            #pragma unroll
            for (int r = 0; r < 4; ++r)
                ao[bo + h * 65536 + (long)(l0 + quad * 4 + r) * 64 + dt * 16 + n16]
                    = f2bf(of[i][dt][r]);
    }
}

// ---------- fp32 -> bf16 elementwise ----------
__global__ __launch_bounds__(256) void convert_f2b(
    const float* __restrict__ in, u16* __restrict__ out)
{
    long i = ((long)blockIdx.x * 256 + threadIdx.x) * 4;
    fx4 v = *(const fx4*)(in + i);
    uint2 o;
    o.x = (unsigned)f2bf(v[0]) | ((unsigned)f2bf(v[1]) << 16);
    o.y = (unsigned)f2bf(v[2]) | ((unsigned)f2bf(v[3]) << 16);
    *(uint2*)(out + i) = o;
}

// ---------- fp32 [R][C] -> bf16 transposed [C][R] ----------
__global__ __launch_bounds__(256) void transpose_f2b(
    const float* __restrict__ in, u16* __restrict__ out, int R, int C)
{
    __shared__ float t[32][33];
    int c0 = blockIdx.x * 32, r0 = blockIdx.y * 32;
    int tx = threadIdx.x & 31, ty = threadIdx.x >> 5;
    #pragma unroll
    for (int i = 0; i < 4; ++i)
        t[ty + i * 8][tx] = in[(long)(r0 + ty + i * 8) * C + c0 + tx];
    __syncthreads();
    #pragma unroll
    for (int i = 0; i < 4; ++i)
        out[(long)(c0 + ty + i * 8) * R + r0 + tx] = f2bf(t[tx][ty + i * 8]);
}

// ---------- bf16 batched transpose ----------
__global__ __launch_bounds__(256) void transpose_bf(
    const u16* __restrict__ in, u16* __restrict__ out, int R, int C)
{
    __shared__ u16 t[32][33];
    long zoff = (long)blockIdx.z * (long)R * (long)C;
    in += zoff; out += zoff;
    int c0 = blockIdx.x * 32, r0 = blockIdx.y * 32;
    int tx = threadIdx.x & 31, ty = threadIdx.x >> 5;
    #pragma unroll
    for (int i = 0; i < 4; ++i)
        t[ty + i * 8][tx] = in[(long)(r0 + ty + i * 8) * C + c0 + tx];
    __syncthreads();
    #pragma unroll
    for (int i = 0; i < 4; ++i)
        out[(long)(c0 + ty + i * 8) * R + r0 + tx] = t[tx][ty + i * 8];
}

// ---------- pack biases fp32 -> bf16 [bq|bk|bv|bc|b1|b2] ----------
__global__ __launch_bounds__(256) void pack_bias(
    const float* bq, const float* bk, const float* bv, const float* bc,
    const float* b1, const float* b2, u16* __restrict__ out)
{
    int i = blockIdx.x * 256 + threadIdx.x;
    float v;
    if      (i < 1024) v = bq[i];
    else if (i < 2048) v = bk[i - 1024];
    else if (i < 3072) v = bv[i - 2048];
    else if (i < 4096) v = bc[i - 3072];
    else if (i < 8192) v = b1[i - 4096];
    else               v = b2[i - 8192];
    out[i] = f2bf(v);
}

// ---------- LayerNorm (ddof=1, /(std+eps)) ----------
__global__ __launch_bounds__(256) void layernorm_row(
    const u16* __restrict__ in, const float* __restrict__ g,
    const float* __restrict__ be, void* __restrict__ out, int outF32)
{
    int wave = threadIdx.x >> 6, lane = threadIdx.x & 63;
    long row = (long)blockIdx.x * 4 + wave;
    const u16* p = in + row * 1024 + lane * 16;

    float x[16];
    uint4 a = ((const uint4*)p)[0], b = ((const uint4*)p)[1];
    {
        unsigned u;
        u = a.x; x[0] = bf2f(u & 0xffff);  x[1] = bf2f(u >> 16);
        u = a.y; x[2] = bf2f(u & 0xffff);  x[3] = bf2f(u >> 16);
        u = a.z; x[4] = bf2f(u & 0xffff);  x[5] = bf2f(u >> 16);
        u = a.w; x[6] = bf2f(u & 0xffff);  x[7] = bf2f(u >> 16);
        u = b.x; x[8] = bf2f(u & 0xffff);  x[9] = bf2f(u >> 16);
        u = b.y; x[10] = bf2f(u & 0xffff); x[11] = bf2f(u >> 16);
        u = b.z; x[12] = bf2f(u & 0xffff); x[13] = bf2f(u >> 16);
        u = b.w; x[14] = bf2f(u & 0xffff); x[15] = bf2f(u >> 16);
    }
    float s = 0.f, ss = 0.f;
    #pragma unroll
    for (int i = 0; i < 16; ++i) { s += x[i]; ss += x[i] * x[i]; }
    #pragma unroll
    for (int o = 32; o >= 1; o >>= 1) { s += __shfl_down(s, o); ss += __shfl_down(ss, o); }
    s = __shfl(s, 0); ss = __shfl(ss, 0);
    float mean = s * (1.f / 1024.f);
    float var  = fmaxf((ss - 1024.f * mean * mean) * (1.f / 1023.f), 0.f);
    float rinv = 1.f / (sqrtf(var) + 1e-12f);

    int col = lane * 16;
    if (outF32) {
        float* ov = (float*)out + row * 1024 + col;
        #pragma unroll
        for (int i = 0; i < 16; ++i)
            ov[i] = g[col + i] * ((x[i] - mean) * rinv) + be[col + i];
    } else {
        u16* ov = (u16*)out + row * 1024 + col;
        #pragma unroll
        for (int i = 0; i < 16; ++i)
            ov[i] = f2bf(g[col + i] * ((x[i] - mean) * rinv) + be[col + i]);
    }
}

// ---------- launch ----------
// ws map (MB; peak 96 + 18KB bias — exactly the round-5 proven extent):
//  [0,16)  xb -> ao (head-major attn out)
//  [16,22) wqkvT  [22,24) wcT
//  [24,40) qb -> t0/x1
//  [40,56) kb -> fh lower   [56,72) vb -> fh upper
//  [72,88) kt (reshape-view K_t, all b) -> w1T/w2T post-attention
//  [88,96) vt half-buffer (4 b at a time) -> pre2 (FFN phase)
//  [96,+18KB) packed biases
extern "C" void kernel_launch(void* const* d_in, const int* in_sizes, int n_in,
                              void* d_out, int out_size, void* d_ws, size_t ws_size,
                              hipStream_t stream)
{
    const float* xf  = (const float*)d_in[0];
    const int* mask  = (const int*)d_in[1];
    const float* wq = (const float*)d_in[2];  const float* bq = (const float*)d_in[3];
    const float* wk = (const float*)d_in[4];  const float* bk = (const float*)d_in[5];
    const float* wv = (const float*)d_in[6];  const float* bv = (const float*)d_in[7];
    const float* wc = (const float*)d_in[8];  const float* bc = (const float*)d_in[9];
    const float* g1 = (const float*)d_in[10]; const float* be1 = (const float*)d_in[11];
    const float* w1 = (const float*)d_in[12]; const float* b1 = (const float*)d_in[13];
    const float* w2 = (const float*)d_in[14]; const float* b2 = (const float*)d_in[15];
    const float* g2 = (const float*)d_in[16]; const float* be2 = (const float*)d_in[17];

    char* ws = (char*)d_ws;
    const long MB = 1 << 20;
    u16* xb    = (u16*)(ws + 0 * MB);
    u16* wqkvT = (u16*)(ws + 16 * MB);
    u16* wcT   = (u16*)(ws + 22 * MB);
    u16* qb    = (u16*)(ws + 24 * MB);
    u16* kb    = (u16*)(ws + 40 * MB);
    u16* vb    = (u16*)(ws + 56 * MB);
    u16* kt    = (u16*)(ws + 72 * MB);
    u16* vth   = (u16*)(ws + 88 * MB);     // half-V^T (4 b)
    u16* biasp = (u16*)(ws + 96 * MB);
    u16* ao   = xb;
    u16* t0   = qb;
    u16* fh   = kb;
    u16* w1T  = (u16*)(ws + 72 * MB);      // overlay kt post-attention
    u16* w2T  = (u16*)(ws + 80 * MB);
    u16* pre2 = (u16*)(ws + 88 * MB);      // overlay vth in FFN phase

    dim3 blk(256);
    const long M1 = 1048576;

    // phase 0: conversions
    convert_f2b<<<dim3(8192), blk, 0, stream>>>(xf, xb);
    transpose_f2b<<<dim3(32, 32), blk, 0, stream>>>(wq, wqkvT, 1024, 1024);
    transpose_f2b<<<dim3(32, 32), blk, 0, stream>>>(wk, wqkvT + M1, 1024, 1024);
    transpose_f2b<<<dim3(32, 32), blk, 0, stream>>>(wv, wqkvT + 2 * M1, 1024, 1024);
    transpose_f2b<<<dim3(32, 32), blk, 0, stream>>>(wc, wcT, 1024, 1024);
    pack_bias<<<dim3(36), blk, 0, stream>>>(bq, bk, bv, bc, b1, b2, biasp);

    // phase 1: fused QKV
    gemm_bt<128><<<dim3(8, 64, 3), blk, 0, stream>>>(
        xb, 0, 1024, wqkvT, M1, 1024, qb, 8 * M1, 1024, 1024,
        biasp, 1024, nullptr, 0, 0, 1.f, 0);

    // phase 2: kt = reshape-view K_t transposed to [m][d], all (b,h)  [round-3 proven]
    transpose_bf<<<dim3(32, 2, 128), blk, 0, stream>>>(kb, kt, 64, 1024);

    // phase 3: fused attention, two 4-batch groups (vt half-buffer at [88,96))
    for (int g = 0; g < 2; ++g) {
        long go = (long)g * 4 * M1;
        transpose_bf<<<dim3(2, 32, 64), blk, 0, stream>>>(vb + go, vth, 1024, 64);
        attn_fused<<<dim3(64, 4), blk, 0, stream>>>(
            qb + go, kt + go, vth, mask + go, ao + go);
    }

    // phase 4: out-proj + bias + resid(x) -> t0 ; LN1 in-place
    gemm_bt<128><<<dim3(8, 64, 1), blk, 0, stream>>>(
        ao, 0, 1024, wcT, 0, 1024, t0, 0, 1024, 1024,
        biasp + 3072, 0, xf, 1, 0, 1.f, 0);
    layernorm_row<<<dim3(2048), blk, 0, stream>>>(t0, g1, be1, t0, 0);

    // phase 5: FFN weight transposes into dead kt region
    transpose_f2b<<<dim3(128, 32), blk, 0, stream>>>(w1, w1T, 1024, 4096);
    transpose_f2b<<<dim3(32, 128), blk, 0, stream>>>(w2, w2T, 4096, 1024);

    // phase 6: FFN + LN2, 2 chunks of 4096 rows
    for (int c = 0; c < 2; ++c) {
        long r0 = (long)c * 4096 * 1024;
        gemm_bt<128><<<dim3(32, 32, 1), blk, 0, stream>>>(
            t0 + r0, 0, 1024, w1T, 0, 1024, fh, 0, 4096, 1024,
            biasp + 4096, 0, nullptr, 0, 0, 1.f, 1);
        gemm_bt<64><<<dim3(16, 32, 1), blk, 0, stream>>>(
            fh, 0, 4096, w2T, 0, 4096, pre2, 0, 1024, 4096,
            biasp + 8192, 0, t0 + r0, 0, 0, 1.f, 0);
        layernorm_row<<<dim3(1024), blk, 0, stream>>>(
            pre2, g2, be2, (float*)d_out + r0, 1);
    }
}